// Round 1
// baseline (159.549 us; speedup 1.0000x reference)
//
#include <hip/hip_runtime.h>

typedef __attribute__((ext_vector_type(8))) __bf16 bf16x8;
typedef __attribute__((ext_vector_type(4))) float f32x4;

#define B_ 16
#define S_ 1024
#define D_ 1024
#define R_ 128

// proj [D][R] fp32  ->  projT [R][D] bf16  (transpose + cast, LDS tiled)
__global__ __launch_bounds__(256) void k_transpose(const float* __restrict__ proj,
                                                   __bf16* __restrict__ projT) {
    __shared__ __bf16 tile[64][66];  // +2 pad: odd dword stride breaks bank aliasing
    const int k0 = blockIdx.x * 64;
    const int r0 = blockIdx.y * 64;
#pragma unroll
    for (int it = 0; it < 16; ++it) {
        int idx = it * 256 + threadIdx.x;
        int kk = idx >> 6, rr = idx & 63;
        tile[kk][rr] = (__bf16)proj[(size_t)(k0 + kk) * R_ + (r0 + rr)];
    }
    __syncthreads();
#pragma unroll
    for (int it = 0; it < 16; ++it) {
        int idx = it * 256 + threadIdx.x;
        int rr = idx >> 6, kk = idx & 63;
        projT[(size_t)(r0 + rr) * D_ + (k0 + kk)] = tile[kk][rr];
    }
}

// t = batch @ proj (bf16 MFMA, fp32 accum) + bf16 t + sq_norms.
// v3: software-pipelined. Same decomposition as v2 (block = 16 rows, 4 waves
// each own a K=256 slice, LDS reduction), but next iteration's A (HBM) and
// B (L2) fragments are prefetched into a second register set while the
// current iteration's MFMAs run. v2's VGPR_Count=52 forced the compiler to
// recycle load-dest registers -> vmcnt wait per load -> 95% stall.
__global__ __launch_bounds__(256, 4) void k_proj(const float* __restrict__ batch,
                                                 const __bf16* __restrict__ projT,
                                                 __bf16* __restrict__ t,
                                                 float* __restrict__ sqn) {
    const int wave = threadIdx.x >> 6;
    const int lane = threadIdx.x & 63;
    const int ln = lane & 15;   // A-row / D-col selector
    const int q  = lane >> 4;   // quad: k-chunk selector (input), row-group (output)
    const int m0 = blockIdx.x * 16;
    const int kbase = wave * 256;   // this wave's K slice
    const float*  arow = batch + (size_t)(m0 + ln) * D_ + kbase + q * 8;
    const __bf16* brow = projT + (size_t)ln * D_ + kbase + q * 8;

    f32x4 acc[8];
#pragma unroll
    for (int ni = 0; ni < 8; ++ni) acc[ni] = f32x4{0.f, 0.f, 0.f, 0.f};

    // Pipeline registers: current + next fragment sets.
    float4 a_lo, a_hi, na_lo, na_hi;
    bf16x8 bc[8], bn[8];

    // Prologue: iteration 0 fragments.
    a_lo = *(const float4*)(arow);
    a_hi = *(const float4*)(arow + 4);
#pragma unroll
    for (int ni = 0; ni < 8; ++ni)
        bc[ni] = *(const bf16x8*)(brow + (size_t)ni * 16 * D_);

#pragma unroll
    for (int it = 0; it < 8; ++it) {
        // Issue next iteration's loads before consuming current fragments.
        if (it < 7) {
            const float* ap = arow + (it + 1) * 32;
            na_lo = *(const float4*)ap;
            na_hi = *(const float4*)(ap + 4);
            const __bf16* bp = brow + (it + 1) * 32;
#pragma unroll
            for (int ni = 0; ni < 8; ++ni)
                bn[ni] = *(const bf16x8*)(bp + (size_t)ni * 16 * D_);
        }
        bf16x8 af;
        af[0] = (__bf16)a_lo.x; af[1] = (__bf16)a_lo.y;
        af[2] = (__bf16)a_lo.z; af[3] = (__bf16)a_lo.w;
        af[4] = (__bf16)a_hi.x; af[5] = (__bf16)a_hi.y;
        af[6] = (__bf16)a_hi.z; af[7] = (__bf16)a_hi.w;
#pragma unroll
        for (int ni = 0; ni < 8; ++ni)
            acc[ni] = __builtin_amdgcn_mfma_f32_16x16x32_bf16(af, bc[ni], acc[ni], 0, 0, 0);
        if (it < 7) {
            a_lo = na_lo; a_hi = na_hi;
#pragma unroll
            for (int ni = 0; ni < 8; ++ni) bc[ni] = bn[ni];
        }
    }

    // Cross-wave K reduction through LDS. red[w][ni][lane] is one f32x4 (16 B
    // per lane, lane-sequential -> conflict-free).
    __shared__ f32x4 red[4][8][64];
    __shared__ float sqpart[4][16];
#pragma unroll
    for (int ni = 0; ni < 8; ++ni) red[wave][ni][lane] = acc[ni];
    __syncthreads();

    // Each wave finalizes 2 ni-tiles (cols 32*wave .. 32*wave+31).
    float sq[4] = {0.f, 0.f, 0.f, 0.f};
#pragma unroll
    for (int p = 0; p < 2; ++p) {
        const int ni = wave * 2 + p;
        f32x4 v = red[0][ni][lane];
#pragma unroll
        for (int w = 1; w < 4; ++w) {
            f32x4 u = red[w][ni][lane];
            v[0] += u[0]; v[1] += u[1]; v[2] += u[2]; v[3] += u[3];
        }
        // D mapping: col = ni*16 + ln, row = q*4 + r
#pragma unroll
        for (int r = 0; r < 4; ++r) {
            __bf16 h = (__bf16)v[r];
            t[(size_t)(m0 + q * 4 + r) * R_ + ni * 16 + ln] = h;
            float f = (float)h;
            sq[r] += f * f;  // sq_norm from *rounded* t: keeps diagonal exact vs gram
        }
    }
    // reduce sq across the 16 lanes (ln) sharing each row -> partial over 32 cols
#pragma unroll
    for (int r = 0; r < 4; ++r) {
#pragma unroll
        for (int off = 1; off < 16; off <<= 1)
            sq[r] += __shfl_xor(sq[r], off, 64);
    }
    if (ln == 0) {
#pragma unroll
        for (int r = 0; r < 4; ++r) sqpart[wave][q * 4 + r] = sq[r];
    }
    __syncthreads();
    if (threadIdx.x < 16) {
        float s = sqpart[0][threadIdx.x] + sqpart[1][threadIdx.x] +
                  sqpart[2][threadIdx.x] + sqpart[3][threadIdx.x];
        sqn[m0 + threadIdx.x] = s;
    }
}

// Per batch: cross = t @ t^T; out = max(0, sqn_i + sqn_j - 2*cross).
// Grid (8,8,16); block 256 thr = 4 waves in 2x2; each wave a 64x64 tile; K=128.
// v2: software-pipelined k-loop (prefetch next k-step's 8 fragments into a
// second register set during the current 16 MFMAs).
__global__ __launch_bounds__(256) void k_gram(const __bf16* __restrict__ t,
                                              const float* __restrict__ sqn,
                                              float* __restrict__ out) {
    const int b = blockIdx.z;
    const int wave = threadIdx.x >> 6;
    const int lane = threadIdx.x & 63;
    const int ln = lane & 15;
    const int q  = lane >> 4;
    const int wi = wave >> 1, wj = wave & 1;
    const int i0 = blockIdx.y * 128 + wi * 64;
    const int j0 = blockIdx.x * 128 + wj * 64;
    const __bf16* tb = t + (size_t)b * S_ * R_;
    const float* sqb = sqn + (size_t)b * S_;

    const __bf16* ti = tb + (size_t)(i0 + ln) * R_ + q * 8;
    const __bf16* tj = tb + (size_t)(j0 + ln) * R_ + q * 8;

    f32x4 acc[4][4];
#pragma unroll
    for (int mi = 0; mi < 4; ++mi)
#pragma unroll
        for (int ni = 0; ni < 4; ++ni) acc[mi][ni] = f32x4{0.f, 0.f, 0.f, 0.f};

    float sqj[4];
#pragma unroll
    for (int ni = 0; ni < 4; ++ni) sqj[ni] = sqb[j0 + ni * 16 + ln];

    bf16x8 ac[4], bc[4], an[4], bn[4];
#pragma unroll
    for (int mi = 0; mi < 4; ++mi) ac[mi] = *(const bf16x8*)(ti + (size_t)mi * 16 * R_);
#pragma unroll
    for (int ni = 0; ni < 4; ++ni) bc[ni] = *(const bf16x8*)(tj + (size_t)ni * 16 * R_);

#pragma unroll
    for (int it = 0; it < 4; ++it) {
        if (it < 3) {
            const __bf16* tin = ti + (it + 1) * 32;
            const __bf16* tjn = tj + (it + 1) * 32;
#pragma unroll
            for (int mi = 0; mi < 4; ++mi) an[mi] = *(const bf16x8*)(tin + (size_t)mi * 16 * R_);
#pragma unroll
            for (int ni = 0; ni < 4; ++ni) bn[ni] = *(const bf16x8*)(tjn + (size_t)ni * 16 * R_);
        }
#pragma unroll
        for (int mi = 0; mi < 4; ++mi)
#pragma unroll
            for (int ni = 0; ni < 4; ++ni)
                acc[mi][ni] = __builtin_amdgcn_mfma_f32_16x16x32_bf16(
                    ac[mi], bc[ni], acc[mi][ni], 0, 0, 0);
        if (it < 3) {
#pragma unroll
            for (int mi = 0; mi < 4; ++mi) ac[mi] = an[mi];
#pragma unroll
            for (int ni = 0; ni < 4; ++ni) bc[ni] = bn[ni];
        }
    }

    float* outb = out + (size_t)b * S_ * S_;
#pragma unroll
    for (int mi = 0; mi < 4; ++mi) {
#pragma unroll
        for (int r = 0; r < 4; ++r) {
            const int i = i0 + mi * 16 + q * 4 + r;
            const float si = sqb[i];
            float* orow = outb + (size_t)i * S_ + j0;
#pragma unroll
            for (int ni = 0; ni < 4; ++ni) {
                float v = si + sqj[ni] - 2.f * acc[mi][ni][r];
                orow[ni * 16 + ln] = fmaxf(v, 0.f);
            }
        }
    }
}

extern "C" void kernel_launch(void* const* d_in, const int* in_sizes, int n_in,
                              void* d_out, int out_size, void* d_ws, size_t ws_size,
                              hipStream_t stream) {
    const float* batch = (const float*)d_in[0];  // [16,1024,1024] fp32
    const float* proj  = (const float*)d_in[1];  // [1024,128] fp32
    float* out = (float*)d_out;                  // [16,1024,1024] fp32

    char* ws = (char*)d_ws;
    __bf16* t     = (__bf16*)ws;                                   // 16384x128 bf16 = 4 MB
    __bf16* projT = (__bf16*)(ws + (size_t)B_ * S_ * R_ * 2);      // 128x1024 bf16 = 256 KB
    float*  sqn   = (float*)(ws + (size_t)B_ * S_ * R_ * 2
                                + (size_t)R_ * D_ * 2);            // 16384 fp32 = 64 KB

    k_transpose<<<dim3(D_ / 64, R_ / 64), 256, 0, stream>>>(proj, projT);
    k_proj<<<dim3((B_ * S_) / 16), 256, 0, stream>>>(batch, projT, t, sqn);
    k_gram<<<dim3(S_ / 128, S_ / 128, B_), 256, 0, stream>>>(t, sqn, out);
}

// Round 3
// 154.425 us; speedup vs baseline: 1.0332x; 1.0332x over previous
//
#include <hip/hip_runtime.h>

typedef __attribute__((ext_vector_type(8))) __bf16 bf16x8;
typedef __attribute__((ext_vector_type(4))) float f32x4;

#define B_ 16
#define S_ 1024
#define D_ 1024
#define R_ 128

// proj [D][R] fp32  ->  projT [R][D] bf16  (transpose + cast, LDS tiled)
__global__ __launch_bounds__(256) void k_transpose(const float* __restrict__ proj,
                                                   __bf16* __restrict__ projT) {
    __shared__ __bf16 tile[64][66];  // +2 pad: odd dword stride breaks bank aliasing
    const int k0 = blockIdx.x * 64;
    const int r0 = blockIdx.y * 64;
#pragma unroll
    for (int it = 0; it < 16; ++it) {
        int idx = it * 256 + threadIdx.x;
        int kk = idx >> 6, rr = idx & 63;
        tile[kk][rr] = (__bf16)proj[(size_t)(k0 + kk) * R_ + (r0 + rr)];
    }
    __syncthreads();
#pragma unroll
    for (int it = 0; it < 16; ++it) {
        int idx = it * 256 + threadIdx.x;
        int rr = idx >> 6, kk = idx & 63;
        projT[(size_t)(r0 + rr) * D_ + (k0 + kk)] = tile[kk][rr];
    }
}

// t = batch @ proj (bf16 MFMA, fp32 accum) + bf16 t + sq_norms.
// v5: burst-load + sched_barrier. v3's reg double-buffer was collapsed by the
// scheduler (VGPR stayed 60 -> loads re-sunk next to uses -> serial latency).
// Now each K=64 chunk issues ALL 20 loads (4 A float4 + 16 B bf16x8) into
// distinct registers, then __builtin_amdgcn_sched_barrier(0) forbids sinking
// them past the compute. Compiler must emit staged vmcnt drains with 20 loads
// in flight per wave. Accumulation order per acc[ni] is unchanged (k ascending)
// -> bitwise-identical output to v2.
__global__ __launch_bounds__(256, 3) void k_proj(const float* __restrict__ batch,
                                                 const __bf16* __restrict__ projT,
                                                 __bf16* __restrict__ t,
                                                 float* __restrict__ sqn) {
    const int wave = threadIdx.x >> 6;
    const int lane = threadIdx.x & 63;
    const int ln = lane & 15;   // A-row / D-col selector
    const int q  = lane >> 4;   // quad: k-chunk selector (input), row-group (output)
    const int m0 = blockIdx.x * 16;
    const int kbase = wave * 256;   // this wave's K slice
    const float*  arow = batch + (size_t)(m0 + ln) * D_ + kbase + q * 8;
    const __bf16* brow = projT + (size_t)ln * D_ + kbase + q * 8;

    f32x4 acc[8];
#pragma unroll
    for (int ni = 0; ni < 8; ++ni) acc[ni] = f32x4{0.f, 0.f, 0.f, 0.f};

    // 4 chunks of K=64 (2 k-steps of 32 each).
#pragma unroll
    for (int c = 0; c < 4; ++c) {
        const float*  ap = arow + c * 64;
        const __bf16* bp = brow + c * 64;
        // ---- load burst: A first (needed first), then B in k-step order ----
        float4 a00 = *(const float4*)(ap);
        float4 a01 = *(const float4*)(ap + 4);
        float4 a10 = *(const float4*)(ap + 32);
        float4 a11 = *(const float4*)(ap + 36);
        bf16x8 b0[8], b1[8];
#pragma unroll
        for (int ni = 0; ni < 8; ++ni)
            b0[ni] = *(const bf16x8*)(bp + (size_t)ni * 16 * D_);
#pragma unroll
        for (int ni = 0; ni < 8; ++ni)
            b1[ni] = *(const bf16x8*)(bp + (size_t)ni * 16 * D_ + 32);
        __builtin_amdgcn_sched_barrier(0);  // no load sinks past this point
        // ---- compute ----
        bf16x8 af0, af1;
        af0[0] = (__bf16)a00.x; af0[1] = (__bf16)a00.y;
        af0[2] = (__bf16)a00.z; af0[3] = (__bf16)a00.w;
        af0[4] = (__bf16)a01.x; af0[5] = (__bf16)a01.y;
        af0[6] = (__bf16)a01.z; af0[7] = (__bf16)a01.w;
        af1[0] = (__bf16)a10.x; af1[1] = (__bf16)a10.y;
        af1[2] = (__bf16)a10.z; af1[3] = (__bf16)a10.w;
        af1[4] = (__bf16)a11.x; af1[5] = (__bf16)a11.y;
        af1[6] = (__bf16)a11.z; af1[7] = (__bf16)a11.w;
#pragma unroll
        for (int ni = 0; ni < 8; ++ni)
            acc[ni] = __builtin_amdgcn_mfma_f32_16x16x32_bf16(af0, b0[ni], acc[ni], 0, 0, 0);
#pragma unroll
        for (int ni = 0; ni < 8; ++ni)
            acc[ni] = __builtin_amdgcn_mfma_f32_16x16x32_bf16(af1, b1[ni], acc[ni], 0, 0, 0);
    }

    // Cross-wave K reduction through LDS. red[w][ni][lane] is one f32x4 (16 B
    // per lane, lane-sequential -> conflict-free).
    __shared__ f32x4 red[4][8][64];
    __shared__ float sqpart[4][16];
#pragma unroll
    for (int ni = 0; ni < 8; ++ni) red[wave][ni][lane] = acc[ni];
    __syncthreads();

    // Each wave finalizes 2 ni-tiles (cols 32*wave .. 32*wave+31).
    float sq[4] = {0.f, 0.f, 0.f, 0.f};
#pragma unroll
    for (int p = 0; p < 2; ++p) {
        const int ni = wave * 2 + p;
        f32x4 v = red[0][ni][lane];
#pragma unroll
        for (int w = 1; w < 4; ++w) {
            f32x4 u = red[w][ni][lane];
            v[0] += u[0]; v[1] += u[1]; v[2] += u[2]; v[3] += u[3];
        }
        // D mapping: col = ni*16 + ln, row = q*4 + r
#pragma unroll
        for (int r = 0; r < 4; ++r) {
            __bf16 h = (__bf16)v[r];
            t[(size_t)(m0 + q * 4 + r) * R_ + ni * 16 + ln] = h;
            float f = (float)h;
            sq[r] += f * f;  // sq_norm from *rounded* t: keeps diagonal exact vs gram
        }
    }
    // reduce sq across the 16 lanes (ln) sharing each row -> partial over 32 cols
#pragma unroll
    for (int r = 0; r < 4; ++r) {
#pragma unroll
        for (int off = 1; off < 16; off <<= 1)
            sq[r] += __shfl_xor(sq[r], off, 64);
    }
    if (ln == 0) {
#pragma unroll
        for (int r = 0; r < 4; ++r) sqpart[wave][q * 4 + r] = sq[r];
    }
    __syncthreads();
    if (threadIdx.x < 16) {
        float s = sqpart[0][threadIdx.x] + sqpart[1][threadIdx.x] +
                  sqpart[2][threadIdx.x] + sqpart[3][threadIdx.x];
        sqn[m0 + threadIdx.x] = s;
    }
}

// Per batch: cross = t @ t^T; out = max(0, sqn_i + sqn_j - 2*cross).
// Grid (8,8,16); block 256 thr = 4 waves in 2x2; each wave a 64x64 tile; K=128.
// v3: full-K burst load. K=128 is only 4 k-steps, so ALL 32 fragments (a[4][4]
// + b[4][4], 128 VGPR) are loaded up front, sched_barrier(0), then 64 MFMAs.
// One latency exposure per wave instead of one per load. Accumulation order
// per acc[mi][ni] unchanged (k ascending) -> bitwise-identical output.
__global__ __launch_bounds__(256, 2) void k_gram(const __bf16* __restrict__ t,
                                                 const float* __restrict__ sqn,
                                                 float* __restrict__ out) {
    const int b = blockIdx.z;
    const int wave = threadIdx.x >> 6;
    const int lane = threadIdx.x & 63;
    const int ln = lane & 15;
    const int q  = lane >> 4;
    const int wi = wave >> 1, wj = wave & 1;
    const int i0 = blockIdx.y * 128 + wi * 64;
    const int j0 = blockIdx.x * 128 + wj * 64;
    const __bf16* tb = t + (size_t)b * S_ * R_;
    const float* sqb = sqn + (size_t)b * S_;

    const __bf16* ti = tb + (size_t)(i0 + ln) * R_ + q * 8;
    const __bf16* tj = tb + (size_t)(j0 + ln) * R_ + q * 8;

    f32x4 acc[4][4];
#pragma unroll
    for (int mi = 0; mi < 4; ++mi)
#pragma unroll
        for (int ni = 0; ni < 4; ++ni) acc[mi][ni] = f32x4{0.f, 0.f, 0.f, 0.f};

    // ---- load burst: all 32 fragments + sqj, in k-step consumption order ----
    bf16x8 a[4][4], bfm[4][4];  // [ks][mi] / [ks][ni]
#pragma unroll
    for (int ks = 0; ks < 4; ++ks) {
#pragma unroll
        for (int mi = 0; mi < 4; ++mi)
            a[ks][mi] = *(const bf16x8*)(ti + (size_t)mi * 16 * R_ + ks * 32);
#pragma unroll
        for (int ni = 0; ni < 4; ++ni)
            bfm[ks][ni] = *(const bf16x8*)(tj + (size_t)ni * 16 * R_ + ks * 32);
    }
    float sqj[4];
#pragma unroll
    for (int ni = 0; ni < 4; ++ni) sqj[ni] = sqb[j0 + ni * 16 + ln];
    __builtin_amdgcn_sched_barrier(0);  // keep all loads in flight before compute

#pragma unroll
    for (int ks = 0; ks < 4; ++ks)
#pragma unroll
        for (int mi = 0; mi < 4; ++mi)
#pragma unroll
            for (int ni = 0; ni < 4; ++ni)
                acc[mi][ni] = __builtin_amdgcn_mfma_f32_16x16x32_bf16(
                    a[ks][mi], bfm[ks][ni], acc[mi][ni], 0, 0, 0);

    float* outb = out + (size_t)b * S_ * S_;
#pragma unroll
    for (int mi = 0; mi < 4; ++mi) {
#pragma unroll
        for (int r = 0; r < 4; ++r) {
            const int i = i0 + mi * 16 + q * 4 + r;
            const float si = sqb[i];
            float* orow = outb + (size_t)i * S_ + j0;
#pragma unroll
            for (int ni = 0; ni < 4; ++ni) {
                float v = si + sqj[ni] - 2.f * acc[mi][ni][r];
                orow[ni * 16 + ln] = fmaxf(v, 0.f);
            }
        }
    }
}

extern "C" void kernel_launch(void* const* d_in, const int* in_sizes, int n_in,
                              void* d_out, int out_size, void* d_ws, size_t ws_size,
                              hipStream_t stream) {
    const float* batch = (const float*)d_in[0];  // [16,1024,1024] fp32
    const float* proj  = (const float*)d_in[1];  // [1024,128] fp32
    float* out = (float*)d_out;                  // [16,1024,1024] fp32

    char* ws = (char*)d_ws;
    __bf16* t     = (__bf16*)ws;                                   // 16384x128 bf16 = 4 MB
    __bf16* projT = (__bf16*)(ws + (size_t)B_ * S_ * R_ * 2);      // 128x1024 bf16 = 256 KB
    float*  sqn   = (float*)(ws + (size_t)B_ * S_ * R_ * 2
                                + (size_t)R_ * D_ * 2);            // 16384 fp32 = 64 KB

    k_transpose<<<dim3(D_ / 64, R_ / 64), 256, 0, stream>>>(proj, projT);
    k_proj<<<dim3((B_ * S_) / 16), 256, 0, stream>>>(batch, projT, t, sqn);
    k_gram<<<dim3(S_ / 128, S_ / 128, B_), 256, 0, stream>>>(t, sqn, out);
}

// Round 4
// 141.527 us; speedup vs baseline: 1.1273x; 1.0911x over previous
//
#include <hip/hip_runtime.h>

typedef __attribute__((ext_vector_type(8))) __bf16 bf16x8;
typedef __attribute__((ext_vector_type(4))) float f32x4;
typedef const __attribute__((address_space(1))) unsigned int gu32;
typedef __attribute__((address_space(3))) unsigned int lu32;

#define B_ 16
#define S_ 1024
#define D_ 1024
#define R_ 128

// Fire-and-forget 16B global->LDS DMA. LDS dest must be the wave-uniform base;
// HW writes base + lane*16. No VGPR destination -> queues arbitrarily deep,
// which is the pipelining mechanism v3/v5's register loads could not get.
__device__ __forceinline__ void gl16(const void* g, void* l) {
    __builtin_amdgcn_global_load_lds((gu32*)g, (lu32*)l, 16, 0, 0);
}

// proj [D][R] fp32  ->  projT [R][D] bf16  (transpose + cast, LDS tiled)
__global__ __launch_bounds__(256) void k_transpose(const float* __restrict__ proj,
                                                   __bf16* __restrict__ projT) {
    __shared__ __bf16 tile[64][66];
    const int k0 = blockIdx.x * 64;
    const int r0 = blockIdx.y * 64;
#pragma unroll
    for (int it = 0; it < 16; ++it) {
        int idx = it * 256 + threadIdx.x;
        int kk = idx >> 6, rr = idx & 63;
        tile[kk][rr] = (__bf16)proj[(size_t)(k0 + kk) * R_ + (r0 + rr)];
    }
    __syncthreads();
#pragma unroll
    for (int it = 0; it < 16; ++it) {
        int idx = it * 256 + threadIdx.x;
        int rr = idx >> 6, kk = idx & 63;
        projT[(size_t)(r0 + rr) * D_ + (k0 + kk)] = tile[kk][rr];
    }
}

// t = batch @ proj. v6: m97-style global_load_lds staging.
// Block: 16 rows x 128 cols, 4 waves each own N=32 (2 ni-tiles), full K=1024
// accumulated per wave in 16 double-buffered chunks of BK=64.
// LDS: A dbuf 2x4KB fp32 @0, B dbuf 2x16KB bf16 @8192 -> 40960 B = 4 blocks/CU.
// XOR swizzles (pre-applied on the global source; LDS stays linear per the
// global_load_lds constraint) break the 16-way ds_read bank conflicts:
//   A [16][64]f32 (256B rows):  byte ^= ((row&7)<<5)|((row&8)<<1)
//   B [128][64]bf16 (128B rows): byte ^= ((row&7)<<4)
__global__ __launch_bounds__(256, 4) void k_proj(const float* __restrict__ batch,
                                                 const __bf16* __restrict__ projT,
                                                 __bf16* __restrict__ t,
                                                 float* __restrict__ sqn) {
    __shared__ __align__(16) char smem[40960];
    const int wave = threadIdx.x >> 6;
    const int lane = threadIdx.x & 63;
    const int ln = lane & 15, q = lane >> 4;
    const int m0 = blockIdx.x * 16;

    // ---- staging source addresses (thread-constant; chunk advances by +256/+128 B) ----
    const int arow = wave * 4 + (lane >> 4);                   // A row 0..15
    const int aswz = ((arow & 7) << 5) | ((arow & 8) << 1);
    const char* ag = (const char*)batch + (size_t)(m0 + arow) * 4096
                   + (((lane & 15) * 16) ^ aswz);
    const int brx = wave * 8 + (lane >> 3);                    // B row base 0..31 (+s*32)
    const int bswz = (brx & 7) << 4;
    const char* bg = (const char*)projT + (size_t)brx * 2048
                   + (((lane & 7) * 16) ^ bswz);
    char* const abuf0 = smem + wave * 1024;                    // wave-uniform LDS bases
    char* const bbuf0 = smem + 8192 + wave * 1024;

    // ---- read-side swizzled offsets ----
    const int raswz = ((ln & 7) << 5) | ((ln & 8) << 1);
    const int rbswz = (ln & 7) << 4;
    const int kq = q * 32;    // A: quad's byte offset within row
    const int kq2 = q * 16;   // B: quad's byte offset within row

    f32x4 acc[2];
    acc[0] = f32x4{0.f, 0.f, 0.f, 0.f};
    acc[1] = f32x4{0.f, 0.f, 0.f, 0.f};

    // stage chunk 0 into buf 0
    gl16(ag, abuf0);
#pragma unroll
    for (int s = 0; s < 4; ++s) gl16(bg + (size_t)s * 65536, bbuf0 + s * 4096);
    __syncthreads();  // vmcnt(0) drain + barrier: buf0 ready

#pragma unroll 2
    for (int c = 0; c < 16; ++c) {
        const int cur = c & 1, nxt = cur ^ 1;
        if (c < 15) {  // prefetch chunk c+1 into the other buffer (fire-and-forget)
            gl16(ag + (c + 1) * 256, abuf0 + nxt * 4096);
#pragma unroll
            for (int s = 0; s < 4; ++s)
                gl16(bg + (size_t)s * 65536 + (c + 1) * 128,
                     bbuf0 + nxt * 16384 + s * 4096);
        }
        const char* ab = smem + cur * 4096 + ln * 256;
        const char* bb = smem + 8192 + cur * 16384 + ln * 128;
#pragma unroll
        for (int ks = 0; ks < 2; ++ks) {
            float4 lo = *(const float4*)(ab + ((ks * 128 + kq) ^ raswz));
            float4 hi = *(const float4*)(ab + ((ks * 128 + kq + 16) ^ raswz));
            bf16x8 af;
            af[0] = (__bf16)lo.x; af[1] = (__bf16)lo.y;
            af[2] = (__bf16)lo.z; af[3] = (__bf16)lo.w;
            af[4] = (__bf16)hi.x; af[5] = (__bf16)hi.y;
            af[6] = (__bf16)hi.z; af[7] = (__bf16)hi.w;
            const int ko = (ks * 64 + kq2) ^ rbswz;
            bf16x8 bf0 = *(const bf16x8*)(bb + (wave * 2 + 0) * 2048 + ko);
            bf16x8 bf1 = *(const bf16x8*)(bb + (wave * 2 + 1) * 2048 + ko);
            acc[0] = __builtin_amdgcn_mfma_f32_16x16x32_bf16(af, bf0, acc[0], 0, 0, 0);
            acc[1] = __builtin_amdgcn_mfma_f32_16x16x32_bf16(af, bf1, acc[1], 0, 0, 0);
        }
        __syncthreads();  // buf[cur] free for next prefetch; buf[nxt] complete
    }

    // ---- epilogue: identical math/order to v2's (each wave owns ni = wave*2+p) ----
    float* sqpart = (float*)smem;  // aliases A buffers (dead after final barrier)
    float sq[4] = {0.f, 0.f, 0.f, 0.f};
#pragma unroll
    for (int p = 0; p < 2; ++p) {
        const int ni = wave * 2 + p;
        f32x4 v = acc[p];
#pragma unroll
        for (int r = 0; r < 4; ++r) {
            __bf16 h = (__bf16)v[r];
            t[(size_t)(m0 + q * 4 + r) * R_ + ni * 16 + ln] = h;
            float f = (float)h;
            sq[r] += f * f;  // sq_norm from rounded t: keeps diagonal exact vs gram
        }
    }
#pragma unroll
    for (int r = 0; r < 4; ++r) {
#pragma unroll
        for (int off = 1; off < 16; off <<= 1)
            sq[r] += __shfl_xor(sq[r], off, 64);
    }
    if (ln == 0) {
#pragma unroll
        for (int r = 0; r < 4; ++r) sqpart[wave * 16 + q * 4 + r] = sq[r];
    }
    __syncthreads();
    if (threadIdx.x < 16) {
        float s = sqpart[threadIdx.x] + sqpart[16 + threadIdx.x] +
                  sqpart[32 + threadIdx.x] + sqpart[48 + threadIdx.x];
        sqn[m0 + threadIdx.x] = s;
    }
}

// Per batch: cross = t @ t^T; out = max(0, sqn_i + sqn_j - 2*cross).
// v6: one-shot global_load_lds staging of both 32KB t-tiles (16 DMAs/thread),
// one barrier, then 4 ksteps x 16 MFMA per wave from LDS. Tile rows are 256B
// -> 16-way bank conflict if linear; same pre-swizzled-source XOR fix:
//   [128][128]bf16 (256B rows): byte ^= ((row&7)<<4)
// Accumulation order per acc element unchanged (ks ascending).
__global__ __launch_bounds__(256, 2) void k_gram(const __bf16* __restrict__ t,
                                                 const float* __restrict__ sqn,
                                                 float* __restrict__ out) {
    __shared__ __align__(16) char smem[65536];  // A-tile @0, B-tile @32768
    const int b = blockIdx.z;
    const int wave = threadIdx.x >> 6, lane = threadIdx.x & 63;
    const int ln = lane & 15, q = lane >> 4;
    const int wi = wave >> 1, wj = wave & 1;
    const int i0b = blockIdx.y * 128, j0b = blockIdx.x * 128;
    const __bf16* tb = t + (size_t)b * S_ * R_;
    const float* sqb = sqn + (size_t)b * S_;

    // ---- staging: 8 issues per tile; rows s*16 + wave*4 + (lane>>4) ----
    const int grow = wave * 4 + (lane >> 4);
    const int gwin = ((lane & 15) * 16) ^ ((grow & 7) << 4);
    const char* agt = (const char*)tb + (size_t)(i0b + grow) * 256 + gwin;
    const char* bgt = (const char*)tb + (size_t)(j0b + grow) * 256 + gwin;
    char* const adst = smem + wave * 1024;
    char* const bdst = smem + 32768 + wave * 1024;
#pragma unroll
    for (int s = 0; s < 8; ++s) gl16(agt + (size_t)s * 4096, adst + s * 4096);
#pragma unroll
    for (int s = 0; s < 8; ++s) gl16(bgt + (size_t)s * 4096, bdst + s * 4096);

    float sqj[4];
#pragma unroll
    for (int ni = 0; ni < 4; ++ni) sqj[ni] = sqb[j0b + wj * 64 + ni * 16 + ln];
    __syncthreads();  // vmcnt(0) drain + barrier: both tiles ready

    f32x4 acc[4][4];
#pragma unroll
    for (int mi = 0; mi < 4; ++mi)
#pragma unroll
        for (int ni = 0; ni < 4; ++ni) acc[mi][ni] = f32x4{0.f, 0.f, 0.f, 0.f};

    const int rsw = (ln & 7) << 4;
    const char* abA = smem + (size_t)(wi * 64 + ln) * 256;
    const char* abB = smem + 32768 + (size_t)(wj * 64 + ln) * 256;
#pragma unroll
    for (int ks = 0; ks < 4; ++ks) {
        const int ko = (ks * 64 + q * 16) ^ rsw;
        bf16x8 af[4], bfm[4];
#pragma unroll
        for (int mi = 0; mi < 4; ++mi)
            af[mi] = *(const bf16x8*)(abA + mi * 4096 + ko);
#pragma unroll
        for (int ni = 0; ni < 4; ++ni)
            bfm[ni] = *(const bf16x8*)(abB + ni * 4096 + ko);
#pragma unroll
        for (int mi = 0; mi < 4; ++mi)
#pragma unroll
            for (int ni = 0; ni < 4; ++ni)
                acc[mi][ni] = __builtin_amdgcn_mfma_f32_16x16x32_bf16(
                    af[mi], bfm[ni], acc[mi][ni], 0, 0, 0);
    }

    const int i0 = i0b + wi * 64, j0 = j0b + wj * 64;
    float* outb = out + (size_t)b * S_ * S_;
#pragma unroll
    for (int mi = 0; mi < 4; ++mi) {
#pragma unroll
        for (int r = 0; r < 4; ++r) {
            const int i = i0 + mi * 16 + q * 4 + r;
            const float si = sqb[i];
            float* orow = outb + (size_t)i * S_ + j0;
#pragma unroll
            for (int ni = 0; ni < 4; ++ni) {
                float v = si + sqj[ni] - 2.f * acc[mi][ni][r];
                orow[ni * 16 + ln] = fmaxf(v, 0.f);
            }
        }
    }
}

extern "C" void kernel_launch(void* const* d_in, const int* in_sizes, int n_in,
                              void* d_out, int out_size, void* d_ws, size_t ws_size,
                              hipStream_t stream) {
    const float* batch = (const float*)d_in[0];  // [16,1024,1024] fp32
    const float* proj  = (const float*)d_in[1];  // [1024,128] fp32
    float* out = (float*)d_out;                  // [16,1024,1024] fp32

    char* ws = (char*)d_ws;
    __bf16* t     = (__bf16*)ws;                                   // 16384x128 bf16 = 4 MB
    __bf16* projT = (__bf16*)(ws + (size_t)B_ * S_ * R_ * 2);      // 128x1024 bf16 = 256 KB
    float*  sqn   = (float*)(ws + (size_t)B_ * S_ * R_ * 2
                                + (size_t)R_ * D_ * 2);            // 16384 fp32 = 64 KB

    k_transpose<<<dim3(D_ / 64, R_ / 64), 256, 0, stream>>>(proj, projT);
    k_proj<<<dim3((B_ * S_) / 16), 256, 0, stream>>>(batch, projT, t, sqn);
    k_gram<<<dim3(S_ / 128, S_ / 128, B_), 256, 0, stream>>>(t, sqn, out);
}

// Round 5
// 141.170 us; speedup vs baseline: 1.1302x; 1.0025x over previous
//
#include <hip/hip_runtime.h>

typedef __attribute__((ext_vector_type(8))) __bf16 bf16x8;
typedef __attribute__((ext_vector_type(4))) float f32x4;
typedef const __attribute__((address_space(1))) unsigned int gu32;
typedef __attribute__((address_space(3))) unsigned int lu32;

#define B_ 16
#define S_ 1024
#define D_ 1024
#define R_ 128

// Fire-and-forget 16B global->LDS DMA (no VGPR dest -> deep HW queue).
__device__ __forceinline__ void gl16(const void* g, void* l) {
    __builtin_amdgcn_global_load_lds((gu32*)g, (lu32*)l, 16, 0, 0);
}

// proj [D][R] fp32  ->  projT [R][D] bf16  (transpose + cast, LDS tiled)
__global__ __launch_bounds__(256) void k_transpose(const float* __restrict__ proj,
                                                   __bf16* __restrict__ projT) {
    __shared__ __bf16 tile[64][66];
    const int k0 = blockIdx.x * 64;
    const int r0 = blockIdx.y * 64;
#pragma unroll
    for (int it = 0; it < 16; ++it) {
        int idx = it * 256 + threadIdx.x;
        int kk = idx >> 6, rr = idx & 63;
        tile[kk][rr] = (__bf16)proj[(size_t)(k0 + kk) * R_ + (r0 + rr)];
    }
    __syncthreads();
#pragma unroll
    for (int it = 0; it < 16; ++it) {
        int idx = it * 256 + threadIdx.x;
        int rr = idx >> 6, kk = idx & 63;
        projT[(size_t)(r0 + rr) * D_ + (k0 + kk)] = tile[kk][rr];
    }
}

// t = batch @ proj. v7: counted-vmcnt pipeline (T4). 512 thr, 32 rows x 128
// cols, 8 waves in 2x4 (each 16 rows x 32 cols, full K). BK=128 -> 8 chunks,
// A segments 512B-contiguous. LDS dbuf 96KB: A(16KB)x2 @0, B(32KB)x2 @32768.
// Main loop NEVER drains vmcnt to 0: stage(c+1) [6 DMA/thread], waitcnt
// vmcnt(6) [chunk c retired, c+1 in flight], s_barrier, compute, s_barrier
// [frees buf for next stage]. v6's __syncthreads vmcnt(0)-drain exposed ~650cy
// of latency every chunk (the m233 2-phase stall).
__global__ __launch_bounds__(512, 2) void k_proj(const float* __restrict__ batch,
                                                 const __bf16* __restrict__ projT,
                                                 __bf16* __restrict__ t,
                                                 float* __restrict__ sqn) {
    __shared__ __align__(16) char smem[98304];
    const int tid = threadIdx.x;
    const int wave = tid >> 6, lane = tid & 63;
    const int ln = lane & 15, q = lane >> 4;
    const int wr = wave >> 2, wc = wave & 3;     // 2x4 wave grid
    const int m0 = blockIdx.x * 32;

    // ---- staging bases (thread-constant; chunk c adds +512B A / +256B B) ----
    // A chunk: [32 rows][512B]; thread stages rows ar0 and ar0+16.
    const int ar0 = wave * 2 + (lane >> 5);      // 0..15
    const int aoff = ((lane & 31) * 16) ^ (((ar0 & 7) << 5) | ((ar0 & 8) << 1));
    const char* ag0 = (const char*)batch + (size_t)(m0 + ar0) * 4096 + aoff;
    const char* ag1 = ag0 + (size_t)16 * 4096;   // (row+16): same swizzle bits
    // B chunk: [128 n][256B]; thread stages n = bn0 + d*32, d=0..3.
    const int bn0 = wave * 4 + (lane >> 4);      // 0..31
    const int boff = ((lane & 15) * 16) ^ ((bn0 & 7) << 4);
    const char* bg = (const char*)projT + (size_t)bn0 * 2048 + boff;
    char* const adst = smem + wave * 1024;            // + buf*16384 + d*8192
    char* const bdst = smem + 32768 + wave * 1024;    // + buf*32768 + d*8192

    // ---- read-side (swizzled) ----
    const int aswz = ((ln & 7) << 5) | ((ln & 8) << 1);
    const int bswz = (ln & 7) << 4;
    const char* arow_l = smem + (size_t)(wr * 16 + ln) * 512;          // + buf*16384
    const char* brow_l = smem + 32768 + (size_t)(wc * 32 + ln) * 256;  // + buf*32768

    f32x4 acc[2];
    acc[0] = f32x4{0.f, 0.f, 0.f, 0.f};
    acc[1] = f32x4{0.f, 0.f, 0.f, 0.f};

#define STAGE_P(c, buf)                                                     \
    do {                                                                    \
        gl16(ag0 + (c) * 512, adst + (buf) * 16384);                        \
        gl16(ag1 + (c) * 512, adst + (buf) * 16384 + 8192);                 \
        gl16(bg + (c) * 256,                 bdst + (buf) * 32768);         \
        gl16(bg + 32 * 2048 + (c) * 256,     bdst + (buf) * 32768 + 8192);  \
        gl16(bg + 64 * 2048 + (c) * 256,     bdst + (buf) * 32768 + 16384); \
        gl16(bg + 96 * 2048 + (c) * 256,     bdst + (buf) * 32768 + 24576); \
    } while (0)

    STAGE_P(0, 0);
#pragma unroll
    for (int c = 0; c < 8; ++c) {
        const int buf = c & 1;
        if (c < 7) {
            STAGE_P(c + 1, buf ^ 1);
            asm volatile("s_waitcnt vmcnt(6)" ::: "memory");  // chunk c done; c+1 in flight
        } else {
            asm volatile("s_waitcnt vmcnt(0)" ::: "memory");
        }
        __builtin_amdgcn_s_barrier();
        const char* Ab = arow_l + buf * 16384;
        const char* Bb = brow_l + buf * 32768;
#pragma unroll
        for (int ks = 0; ks < 4; ++ks) {
            const int ao = ks * 128 + q * 32;
            float4 lo = *(const float4*)(Ab + (ao ^ aswz));
            float4 hi = *(const float4*)(Ab + ((ao + 16) ^ aswz));
            bf16x8 af;
            af[0] = (__bf16)lo.x; af[1] = (__bf16)lo.y;
            af[2] = (__bf16)lo.z; af[3] = (__bf16)lo.w;
            af[4] = (__bf16)hi.x; af[5] = (__bf16)hi.y;
            af[6] = (__bf16)hi.z; af[7] = (__bf16)hi.w;
            const int bo = (ks * 64 + q * 16) ^ bswz;
            bf16x8 b0 = *(const bf16x8*)(Bb + bo);
            bf16x8 b1 = *(const bf16x8*)(Bb + 4096 + bo);   // +16 n-rows
            acc[0] = __builtin_amdgcn_mfma_f32_16x16x32_bf16(af, b0, acc[0], 0, 0, 0);
            acc[1] = __builtin_amdgcn_mfma_f32_16x16x32_bf16(af, b1, acc[1], 0, 0, 0);
        }
        __builtin_amdgcn_s_barrier();   // buf free for the next stage
    }
#undef STAGE_P

    // ---- epilogue: t (bf16) + sq_norms from rounded t ----
    float* sqpart = (float*)smem;   // [4 wc][32 rows]; aliases buf0 (dead)
    float sq[4] = {0.f, 0.f, 0.f, 0.f};
#pragma unroll
    for (int p = 0; p < 2; ++p) {
#pragma unroll
        for (int r = 0; r < 4; ++r) {
            __bf16 h = (__bf16)acc[p][r];
            t[(size_t)(m0 + wr * 16 + q * 4 + r) * R_ + wc * 32 + p * 16 + ln] = h;
            float f = (float)h;
            sq[r] += f * f;
        }
    }
#pragma unroll
    for (int r = 0; r < 4; ++r) {
#pragma unroll
        for (int off = 1; off < 16; off <<= 1)
            sq[r] += __shfl_xor(sq[r], off, 64);
    }
    if (ln == 0) {
#pragma unroll
        for (int r = 0; r < 4; ++r)
            sqpart[wc * 32 + wr * 16 + q * 4 + r] = sq[r];
    }
    __syncthreads();
    if (tid < 32) {
        float s = sqpart[tid] + sqpart[32 + tid] + sqpart[64 + tid] + sqpart[96 + tid];
        sqn[m0 + tid] = s;
    }
}

// Per batch: cross = t @ t^T; out = max(0, sqn_i + sqn_j - 2*cross).
// v7: 2-half counted-vmcnt stage (no buffer reuse -> no race), NT stores.
// LDS 64KB: A0@0 B0@16384 A1@32768 B1@49152, each [128 rows][128B] (one
// K-half), XOR-swizzled (row&7)<<4 on source+read. Accumulation order per
// acc element unchanged (ks ascending) -> identical output to v6.
__global__ __launch_bounds__(256, 2) void k_gram(const __bf16* __restrict__ t,
                                                 const float* __restrict__ sqn,
                                                 float* __restrict__ out) {
    __shared__ __align__(16) char smem[65536];
    const int b = blockIdx.z;
    const int wave = threadIdx.x >> 6, lane = threadIdx.x & 63;
    const int ln = lane & 15, q = lane >> 4;
    const int wi = wave >> 1, wj = wave & 1;
    const int i0b = blockIdx.y * 128, j0b = blockIdx.x * 128;
    const __bf16* tb = t + (size_t)b * S_ * R_;
    const float* sqb = sqn + (size_t)b * S_;

    // sqj first: these 4 VMEM loads retire under the vmcnt(8) wait below.
    float sqj[4];
#pragma unroll
    for (int ni = 0; ni < 4; ++ni) sqj[ni] = sqb[j0b + wj * 64 + ni * 16 + ln];

    // stage addressing: rows grow + d*32, 128B per row per half.
    const int grow = wave * 8 + (lane >> 3);     // 0..31
    const int goff = ((lane & 7) * 16) ^ ((grow & 7) << 4);
    const char* agt = (const char*)tb + (size_t)(i0b + grow) * 256 + goff;
    const char* bgt = (const char*)tb + (size_t)(j0b + grow) * 256 + goff;
    char* const adst = smem + wave * 1024;            // + h*32768 + d*4096
    char* const bdst = smem + 16384 + wave * 1024;

#define STAGE_G(h)                                                        \
    do {                                                                  \
        gl16(agt + (h) * 128,              adst + (h) * 32768);           \
        gl16(agt + 32 * 256 + (h) * 128,   adst + (h) * 32768 + 4096);    \
        gl16(agt + 64 * 256 + (h) * 128,   adst + (h) * 32768 + 8192);    \
        gl16(agt + 96 * 256 + (h) * 128,   adst + (h) * 32768 + 12288);   \
        gl16(bgt + (h) * 128,              bdst + (h) * 32768);           \
        gl16(bgt + 32 * 256 + (h) * 128,   bdst + (h) * 32768 + 4096);    \
        gl16(bgt + 64 * 256 + (h) * 128,   bdst + (h) * 32768 + 8192);    \
        gl16(bgt + 96 * 256 + (h) * 128,   bdst + (h) * 32768 + 12288);   \
    } while (0)

    STAGE_G(0);
    STAGE_G(1);
#undef STAGE_G

    f32x4 acc[4][4];
#pragma unroll
    for (int mi = 0; mi < 4; ++mi)
#pragma unroll
        for (int ni = 0; ni < 4; ++ni) acc[mi][ni] = f32x4{0.f, 0.f, 0.f, 0.f};

    const int rsw = (ln & 7) << 4;
    const char* abA = smem + (size_t)(wi * 64 + ln) * 128;            // + h*32768
    const char* abB = smem + 16384 + (size_t)(wj * 64 + ln) * 128;

#pragma unroll
    for (int h = 0; h < 2; ++h) {
        if (h == 0)
            asm volatile("s_waitcnt vmcnt(8)" ::: "memory");  // half 0 (+sqj) retired
        else
            asm volatile("s_waitcnt vmcnt(0)" ::: "memory");
        __builtin_amdgcn_s_barrier();
        const char* hA = abA + h * 32768;
        const char* hB = abB + h * 32768;
#pragma unroll
        for (int ks = 0; ks < 2; ++ks) {
            const int ko = (ks * 64 + q * 16) ^ rsw;
            bf16x8 af[4], bfm[4];
#pragma unroll
            for (int mi = 0; mi < 4; ++mi)
                af[mi] = *(const bf16x8*)(hA + mi * 2048 + ko);
#pragma unroll
            for (int ni = 0; ni < 4; ++ni)
                bfm[ni] = *(const bf16x8*)(hB + ni * 2048 + ko);
#pragma unroll
            for (int mi = 0; mi < 4; ++mi)
#pragma unroll
                for (int ni = 0; ni < 4; ++ni)
                    acc[mi][ni] = __builtin_amdgcn_mfma_f32_16x16x32_bf16(
                        af[mi], bfm[ni], acc[mi][ni], 0, 0, 0);
        }
    }

    const int i0 = i0b + wi * 64, j0 = j0b + wj * 64;
    float* outb = out + (size_t)b * S_ * S_;
#pragma unroll
    for (int mi = 0; mi < 4; ++mi) {
#pragma unroll
        for (int r = 0; r < 4; ++r) {
            const int i = i0 + mi * 16 + q * 4 + r;
            const float si = sqb[i];
            float* orow = outb + (size_t)i * S_ + j0;
#pragma unroll
            for (int ni = 0; ni < 4; ++ni) {
                float v = si + sqj[ni] - 2.f * acc[mi][ni][r];
                __builtin_nontemporal_store(fmaxf(v, 0.f), &orow[ni * 16 + ln]);
            }
        }
    }
}

extern "C" void kernel_launch(void* const* d_in, const int* in_sizes, int n_in,
                              void* d_out, int out_size, void* d_ws, size_t ws_size,
                              hipStream_t stream) {
    const float* batch = (const float*)d_in[0];  // [16,1024,1024] fp32
    const float* proj  = (const float*)d_in[1];  // [1024,128] fp32
    float* out = (float*)d_out;                  // [16,1024,1024] fp32

    char* ws = (char*)d_ws;
    __bf16* t     = (__bf16*)ws;                                   // 16384x128 bf16 = 4 MB
    __bf16* projT = (__bf16*)(ws + (size_t)B_ * S_ * R_ * 2);      // 128x1024 bf16 = 256 KB
    float*  sqn   = (float*)(ws + (size_t)B_ * S_ * R_ * 2
                                + (size_t)R_ * D_ * 2);            // 16384 fp32 = 64 KB

    k_transpose<<<dim3(D_ / 64, R_ / 64), 256, 0, stream>>>(proj, projT);
    k_proj<<<dim3((B_ * S_) / 32), 512, 0, stream>>>(batch, projT, t, sqn);
    k_gram<<<dim3(S_ / 128, S_ / 128, B_), 256, 0, stream>>>(t, sqn, out);
}

// Round 6
// 138.484 us; speedup vs baseline: 1.1521x; 1.0194x over previous
//
#include <hip/hip_runtime.h>

typedef __attribute__((ext_vector_type(8))) __bf16 bf16x8;
typedef __attribute__((ext_vector_type(4))) float f32x4;
typedef const __attribute__((address_space(1))) unsigned int gu32;
typedef __attribute__((address_space(3))) unsigned int lu32;

#define B_ 16
#define S_ 1024
#define D_ 1024
#define R_ 128

// Fire-and-forget 16B global->LDS DMA (no VGPR dest -> deep HW queue).
__device__ __forceinline__ void gl16(const void* g, void* l) {
    __builtin_amdgcn_global_load_lds((gu32*)g, (lu32*)l, 16, 0, 0);
}

// proj [D][R] fp32  ->  projT [R][D] bf16  (transpose + cast, LDS tiled)
__global__ __launch_bounds__(256) void k_transpose(const float* __restrict__ proj,
                                                   __bf16* __restrict__ projT) {
    __shared__ __bf16 tile[64][66];
    const int k0 = blockIdx.x * 64;
    const int r0 = blockIdx.y * 64;
#pragma unroll
    for (int it = 0; it < 16; ++it) {
        int idx = it * 256 + threadIdx.x;
        int kk = idx >> 6, rr = idx & 63;
        tile[kk][rr] = (__bf16)proj[(size_t)(k0 + kk) * R_ + (r0 + rr)];
    }
    __syncthreads();
#pragma unroll
    for (int it = 0; it < 16; ++it) {
        int idx = it * 256 + threadIdx.x;
        int rr = idx >> 6, kk = idx & 63;
        projT[(size_t)(r0 + rr) * D_ + (k0 + kk)] = tile[kk][rr];
    }
}

// t = batch @ proj. v8 = v6's structure (16 rows x 128 cols, 4 waves split N,
// BK=64, LDS dbuf 40KB -> 4 blocks/CU, 16 waves/CU) with ONLY the sync
// changed: __syncthreads (vmcnt(0) drain = m233 2-phase stall) replaced by
// counted s_waitcnt vmcnt(5) + raw s_barrier. Chunk c+1's 5 DMAs stay in
// flight across the barrier; never drain to 0 in the main loop (T4).
// Swizzles/accumulation order identical to v6 (R4-verified).
//   A [16][64]f32 (256B rows):  byte ^= ((row&7)<<5)|((row&8)<<1)
//   B [128][64]bf16 (128B rows): byte ^= ((row&7)<<4)
__global__ __launch_bounds__(256, 4) void k_proj(const float* __restrict__ batch,
                                                 const __bf16* __restrict__ projT,
                                                 __bf16* __restrict__ t,
                                                 float* __restrict__ sqn) {
    __shared__ __align__(16) char smem[40960];
    const int wave = threadIdx.x >> 6;
    const int lane = threadIdx.x & 63;
    const int ln = lane & 15, q = lane >> 4;
    const int m0 = blockIdx.x * 16;

    // ---- staging source addresses (thread-constant; chunk advances by +256/+128 B) ----
    const int arow = wave * 4 + (lane >> 4);                   // A row 0..15
    const int aswz = ((arow & 7) << 5) | ((arow & 8) << 1);
    const char* ag = (const char*)batch + (size_t)(m0 + arow) * 4096
                   + (((lane & 15) * 16) ^ aswz);
    const int brx = wave * 8 + (lane >> 3);                    // B row base 0..31 (+s*32)
    const int bswz = (brx & 7) << 4;
    const char* bg = (const char*)projT + (size_t)brx * 2048
                   + (((lane & 7) * 16) ^ bswz);
    char* const abuf0 = smem + wave * 1024;                    // wave-uniform LDS bases
    char* const bbuf0 = smem + 8192 + wave * 1024;

    // ---- read-side swizzled offsets ----
    const int raswz = ((ln & 7) << 5) | ((ln & 8) << 1);
    const int rbswz = (ln & 7) << 4;
    const int kq = q * 32;    // A: quad's byte offset within row
    const int kq2 = q * 16;   // B: quad's byte offset within row

    f32x4 acc[2];
    acc[0] = f32x4{0.f, 0.f, 0.f, 0.f};
    acc[1] = f32x4{0.f, 0.f, 0.f, 0.f};

#define STAGE_P(c, buf)                                                      \
    do {                                                                     \
        gl16(ag + (c) * 256, abuf0 + (buf) * 4096);                          \
        gl16(bg + (c) * 128,                 bbuf0 + (buf) * 16384);         \
        gl16(bg + 32 * 2048 + (c) * 128,     bbuf0 + (buf) * 16384 + 4096);  \
        gl16(bg + 64 * 2048 + (c) * 128,     bbuf0 + (buf) * 16384 + 8192);  \
        gl16(bg + 96 * 2048 + (c) * 128,     bbuf0 + (buf) * 16384 + 12288); \
    } while (0)

    STAGE_P(0, 0);   // 5 DMAs outstanding
#pragma unroll
    for (int c = 0; c < 16; ++c) {
        const int buf = c & 1;
        if (c < 15) {
            STAGE_P(c + 1, buf ^ 1);   // 10 outstanding
            asm volatile("s_waitcnt vmcnt(5)" ::: "memory");  // chunk c landed; c+1 in flight
        } else {
            asm volatile("s_waitcnt vmcnt(0)" ::: "memory");
        }
        __builtin_amdgcn_s_barrier();   // all waves' chunk-c DMAs retired
        const char* ab = smem + buf * 4096 + ln * 256;
        const char* bb = smem + 8192 + buf * 16384 + ln * 128;
#pragma unroll
        for (int ks = 0; ks < 2; ++ks) {
            float4 lo = *(const float4*)(ab + ((ks * 128 + kq) ^ raswz));
            float4 hi = *(const float4*)(ab + ((ks * 128 + kq + 16) ^ raswz));
            bf16x8 af;
            af[0] = (__bf16)lo.x; af[1] = (__bf16)lo.y;
            af[2] = (__bf16)lo.z; af[3] = (__bf16)lo.w;
            af[4] = (__bf16)hi.x; af[5] = (__bf16)hi.y;
            af[6] = (__bf16)hi.z; af[7] = (__bf16)hi.w;
            const int ko = (ks * 64 + kq2) ^ rbswz;
            bf16x8 bf0 = *(const bf16x8*)(bb + (wave * 2 + 0) * 2048 + ko);
            bf16x8 bf1 = *(const bf16x8*)(bb + (wave * 2 + 1) * 2048 + ko);
            acc[0] = __builtin_amdgcn_mfma_f32_16x16x32_bf16(af, bf0, acc[0], 0, 0, 0);
            acc[1] = __builtin_amdgcn_mfma_f32_16x16x32_bf16(af, bf1, acc[1], 0, 0, 0);
        }
        __builtin_amdgcn_s_barrier();   // buf free for the next stage
    }
#undef STAGE_P

    // ---- epilogue: identical to v6 (each wave owns ni = wave*2+p) ----
    float* sqpart = (float*)smem;  // aliases A buf0 (dead after final barrier)
    float sq[4] = {0.f, 0.f, 0.f, 0.f};
#pragma unroll
    for (int p = 0; p < 2; ++p) {
        const int ni = wave * 2 + p;
        f32x4 v = acc[p];
#pragma unroll
        for (int r = 0; r < 4; ++r) {
            __bf16 h = (__bf16)v[r];
            t[(size_t)(m0 + q * 4 + r) * R_ + ni * 16 + ln] = h;
            float f = (float)h;
            sq[r] += f * f;  // sq_norm from rounded t: keeps diagonal exact vs gram
        }
    }
#pragma unroll
    for (int r = 0; r < 4; ++r) {
#pragma unroll
        for (int off = 1; off < 16; off <<= 1)
            sq[r] += __shfl_xor(sq[r], off, 64);
    }
    if (ln == 0) {
#pragma unroll
        for (int r = 0; r < 4; ++r) sqpart[wave * 16 + q * 4 + r] = sq[r];
    }
    __syncthreads();
    if (threadIdx.x < 16) {
        float s = sqpart[threadIdx.x] + sqpart[16 + threadIdx.x] +
                  sqpart[32 + threadIdx.x] + sqpart[48 + threadIdx.x];
        sqn[m0 + threadIdx.x] = s;
    }
}

// Per batch: cross = t @ t^T; out = max(0, sqn_i + sqn_j - 2*cross).
// v7 (unchanged): 2-half counted-vmcnt stage (no buffer reuse -> no race),
// NT stores. LDS 64KB: A0@0 B0@16384 A1@32768 B1@49152, each [128 rows][128B]
// (one K-half), XOR-swizzled (row&7)<<4 on source+read.
__global__ __launch_bounds__(256, 2) void k_gram(const __bf16* __restrict__ t,
                                                 const float* __restrict__ sqn,
                                                 float* __restrict__ out) {
    __shared__ __align__(16) char smem[65536];
    const int b = blockIdx.z;
    const int wave = threadIdx.x >> 6, lane = threadIdx.x & 63;
    const int ln = lane & 15, q = lane >> 4;
    const int wi = wave >> 1, wj = wave & 1;
    const int i0b = blockIdx.y * 128, j0b = blockIdx.x * 128;
    const __bf16* tb = t + (size_t)b * S_ * R_;
    const float* sqb = sqn + (size_t)b * S_;

    // sqj first: these 4 VMEM loads retire under the vmcnt(8) wait below.
    float sqj[4];
#pragma unroll
    for (int ni = 0; ni < 4; ++ni) sqj[ni] = sqb[j0b + wj * 64 + ni * 16 + ln];

    // stage addressing: rows grow + d*32, 128B per row per half.
    const int grow = wave * 8 + (lane >> 3);     // 0..31
    const int goff = ((lane & 7) * 16) ^ ((grow & 7) << 4);
    const char* agt = (const char*)tb + (size_t)(i0b + grow) * 256 + goff;
    const char* bgt = (const char*)tb + (size_t)(j0b + grow) * 256 + goff;
    char* const adst = smem + wave * 1024;            // + h*32768 + d*4096
    char* const bdst = smem + 16384 + wave * 1024;

#define STAGE_G(h)                                                        \
    do {                                                                  \
        gl16(agt + (h) * 128,              adst + (h) * 32768);           \
        gl16(agt + 32 * 256 + (h) * 128,   adst + (h) * 32768 + 4096);    \
        gl16(agt + 64 * 256 + (h) * 128,   adst + (h) * 32768 + 8192);    \
        gl16(agt + 96 * 256 + (h) * 128,   adst + (h) * 32768 + 12288);   \
        gl16(bgt + (h) * 128,              bdst + (h) * 32768);           \
        gl16(bgt + 32 * 256 + (h) * 128,   bdst + (h) * 32768 + 4096);    \
        gl16(bgt + 64 * 256 + (h) * 128,   bdst + (h) * 32768 + 8192);    \
        gl16(bgt + 96 * 256 + (h) * 128,   bdst + (h) * 32768 + 12288);   \
    } while (0)

    STAGE_G(0);
    STAGE_G(1);
#undef STAGE_G

    f32x4 acc[4][4];
#pragma unroll
    for (int mi = 0; mi < 4; ++mi)
#pragma unroll
        for (int ni = 0; ni < 4; ++ni) acc[mi][ni] = f32x4{0.f, 0.f, 0.f, 0.f};

    const int rsw = (ln & 7) << 4;
    const char* abA = smem + (size_t)(wi * 64 + ln) * 128;            // + h*32768
    const char* abB = smem + 16384 + (size_t)(wj * 64 + ln) * 128;

#pragma unroll
    for (int h = 0; h < 2; ++h) {
        if (h == 0)
            asm volatile("s_waitcnt vmcnt(8)" ::: "memory");  // half 0 (+sqj) retired
        else
            asm volatile("s_waitcnt vmcnt(0)" ::: "memory");
        __builtin_amdgcn_s_barrier();
        const char* hA = abA + h * 32768;
        const char* hB = abB + h * 32768;
#pragma unroll
        for (int ks = 0; ks < 2; ++ks) {
            const int ko = (ks * 64 + q * 16) ^ rsw;
            bf16x8 af[4], bfm[4];
#pragma unroll
            for (int mi = 0; mi < 4; ++mi)
                af[mi] = *(const bf16x8*)(hA + mi * 2048 + ko);
#pragma unroll
            for (int ni = 0; ni < 4; ++ni)
                bfm[ni] = *(const bf16x8*)(hB + ni * 2048 + ko);
#pragma unroll
            for (int mi = 0; mi < 4; ++mi)
#pragma unroll
                for (int ni = 0; ni < 4; ++ni)
                    acc[mi][ni] = __builtin_amdgcn_mfma_f32_16x16x32_bf16(
                        af[mi], bfm[ni], acc[mi][ni], 0, 0, 0);
        }
    }

    const int i0 = i0b + wi * 64, j0 = j0b + wj * 64;
    float* outb = out + (size_t)b * S_ * S_;
#pragma unroll
    for (int mi = 0; mi < 4; ++mi) {
#pragma unroll
        for (int r = 0; r < 4; ++r) {
            const int i = i0 + mi * 16 + q * 4 + r;
            const float si = sqb[i];
            float* orow = outb + (size_t)i * S_ + j0;
#pragma unroll
            for (int ni = 0; ni < 4; ++ni) {
                float v = si + sqj[ni] - 2.f * acc[mi][ni][r];
                __builtin_nontemporal_store(fmaxf(v, 0.f), &orow[ni * 16 + ln]);
            }
        }
    }
}

extern "C" void kernel_launch(void* const* d_in, const int* in_sizes, int n_in,
                              void* d_out, int out_size, void* d_ws, size_t ws_size,
                              hipStream_t stream) {
    const float* batch = (const float*)d_in[0];  // [16,1024,1024] fp32
    const float* proj  = (const float*)d_in[1];  // [1024,128] fp32
    float* out = (float*)d_out;                  // [16,1024,1024] fp32

    char* ws = (char*)d_ws;
    __bf16* t     = (__bf16*)ws;                                   // 16384x128 bf16 = 4 MB
    __bf16* projT = (__bf16*)(ws + (size_t)B_ * S_ * R_ * 2);      // 128x1024 bf16 = 256 KB
    float*  sqn   = (float*)(ws + (size_t)B_ * S_ * R_ * 2
                                + (size_t)R_ * D_ * 2);            // 16384 fp32 = 64 KB

    k_transpose<<<dim3(D_ / 64, R_ / 64), 256, 0, stream>>>(proj, projT);
    k_proj<<<dim3((B_ * S_) / 16), 256, 0, stream>>>(batch, projT, t, sqn);
    k_gram<<<dim3(S_ / 128, S_ / 128, B_), 256, 0, stream>>>(t, sqn, out);
}